// Round 1
// baseline (271.949 us; speedup 1.0000x reference)
//
#include <hip/hip_runtime.h>
#include <stdint.h>

// Problem constants (fixed by the reference file)
#define N_POS (16 * 65536)   // B * L = 1,048,576 positions
#define NBINS 256
#define HDIM  64

// ROUND 11 THEORY:
//  - Fill kernels hit 6.3 TB/s writing this same buffer class; our kernel's
//    floor is 256 MB write + 4 MB read ~= 43 us. We sit at 268 us (~1 TB/s).
//  - Phase 2 previously paired every float4 store with a GLOBAL gather from
//    the 65.8 KB emb table (L1-thrash, shares vmcnt with stores -> store
//    queue drains behind gather latency). Fix: stage the full emb table in
//    LDS once per block; phase 2 becomes ds_read_b128 -> store, a pure
//    store stream like the fills.
//  - Amortize the 66 KB staging: each block handles 8 tiles of 256 positions
//    (512 blocks = exactly 2/CU; 68.9 KB LDS/block -> 2 resident, 8 waves/CU.
//    Fills saturate write BW at ~10% occupancy, so 8 waves suffice).
//  - x prefetch for next tile issued before the barrier; double-buffered
//    s_tok -> single barrier per tile (tile+2's rewrite is fenced by the
//    intervening tile+1 barrier).

typedef float vfloat4 __attribute__((ext_vector_type(4)));

#define THREADS        256
#define POS_PER_TILE   256
#define TILES          8
#define POS_PER_BLOCK  (POS_PER_TILE * TILES)      // 2048 positions / block
#define NBLOCKS        (N_POS / POS_PER_BLOCK)     // 512 blocks = 2 per CU, exact cover
#define EMB_ROWS       (NBINS + 1)                 // 257
#define EMB_CHUNKS     (EMB_ROWS * 16)             // 4112 float4 chunks = 65,792 B

__global__ __launch_bounds__(THREADS, 2)
void BinEmbedding_49520972923592_kernel(
    const float* __restrict__ x,        // (B*L) fp32
    const float* __restrict__ bins,     // (256) fp32, sorted
    const vfloat4* __restrict__ embv,   // (257,64) fp32 = 16 float4 chunks per row
    vfloat4* __restrict__ out)          // (B*L,64) fp32 = 16 float4 chunks per row
{
    __shared__ vfloat4 s_emb[EMB_CHUNKS];       // 65,792 B — whole emb table
    __shared__ float   s_bins[NBINS];           //  1,024 B
    __shared__ int     s_tok[2][POS_PER_TILE];  //  2,048 B   (total 68,864 B)

    const int tid = threadIdx.x;

    // ---- One-time staging: bins + full emb table into LDS ------------------
    s_bins[tid] = bins[tid];                    // blockDim == NBINS == 256
    for (int c = tid; c < EMB_CHUNKS; c += THREADS)
        s_emb[c] = embv[c];                     // coalesced dwordx4, 16.06/thread

    const long pbase = (long)blockIdx.x * POS_PER_BLOCK;
    float xv = x[pbase + tid];                  // tile 0's x, issued pre-barrier
    __syncthreads();

    for (int tile = 0; tile < TILES; ++tile) {
        // ---- Phase 1: token for this tile's position (1 search / position) --
        // count = #bins <= xv (branchless upper-bound search; NaN -> cnt = 0).
        int cnt = 0;
#pragma unroll
        for (int step = 128; step >= 1; step >>= 1) {
            const int cand = cnt + step;
            cnt = (s_bins[cand - 1] <= xv) ? cand : cnt;
        }
        cnt += (s_bins[NBINS - 1] <= xv) ? 1 : 0;

        // tok = NaN ? 0 : max(count, 1)  (== clamp(searchsorted_right-1, 0)+1)
        s_tok[tile & 1][tid] = (xv != xv) ? 0 : (cnt > 0 ? cnt : 1);

        // prefetch next tile's x so its HBM latency hides under the stores
        if (tile + 1 < TILES)
            xv = x[pbase + (tile + 1) * POS_PER_TILE + tid];

        __syncthreads();

        // ---- Phase 2: pure store stream, fed from LDS ----------------------
        // Iteration i: consecutive threads -> consecutive chunks (wave writes
        // 1 KB contiguous, plain stores). s_emb read: group of 16 lanes reads
        // one 256 B row -> 2-way bank aliasing (free). s_tok: broadcast.
        const int* st = s_tok[tile & 1];
        const long cbase = (pbase + (long)tile * POS_PER_TILE) * 16;
#pragma unroll
        for (int i = 0; i < 16; ++i) {
            const int l = i * THREADS + tid;              // local chunk [0,4096)
            out[cbase + l] = s_emb[st[l >> 4] * 16 + (l & 15)];
        }
        // no trailing barrier: next tile writes the OTHER s_tok buffer; the
        // rewrite of THIS buffer (tile+2) is fenced by tile+1's barrier.
    }
}

extern "C" void kernel_launch(void* const* d_in, const int* in_sizes, int n_in,
                              void* d_out, int out_size, void* d_ws, size_t ws_size,
                              hipStream_t stream) {
    const float*   x    = (const float*)d_in[0];    // (16,65536) fp32
    const float*   bins = (const float*)d_in[1];    // (256,) fp32
    const vfloat4* emb  = (const vfloat4*)d_in[2];  // (257,64) fp32 chunks
    vfloat4* out = (vfloat4*)d_out;                 // (16,65536,64) fp32 chunks

    // 512 blocks x 2048 positions = 1,048,576 = exact cover; 2 blocks/CU.
    const dim3 grid(NBLOCKS), block(THREADS);
    hipLaunchKernelGGL(BinEmbedding_49520972923592_kernel, grid, block, 0, stream,
                       x, bins, emb, out);
}

// Round 2
// 264.362 us; speedup vs baseline: 1.0287x; 1.0287x over previous
//
#include <hip/hip_runtime.h>
#include <stdint.h>

// Problem constants (fixed by the reference file)
#define N_POS (16 * 65536)   // B * L = 1,048,576 positions
#define NBINS 256
#define HDIM  64

// ROUND 12 THEORY:
//  - dur_us includes harness poison fills (our kernel never appears in the
//    top-5 dispatch rows, cutoff ~164 us => kernel < 164 us). Estimated
//    decomposition: ~166 (1 GiB ws fill) + ~43 (out fill) + ~60 (kernel).
//  - R11 neutrality: hipcc emits s_waitcnt vmcnt(0) before every s_barrier;
//    8 per-tile barriers force-drained the store queue 8x per block --
//    trading R10's gather-vmcnt stalls for barrier-drain stalls. Net zero.
//  - Fix: compute ALL 2048 tokens up front (8 searches/thread, ILP-parallel
//    dependent-LDS chains), ONE barrier, then 128 uninterrupted float4
//    stores/thread fed exclusively from LDS (lgkmcnt only, no vmcnt loads,
//    no barriers) until endpgm. Store stream now structurally identical to
//    the 6.45 TB/s fill kernel.
//  - emb LDS read pattern: per store instruction a wave reads 4 rows x 256 B
//    contiguous = 8 words/bank uniform == contiguous-1KB pattern, conflict-
//    free; LDS read BW ~5 us total per CU, not a limiter.

typedef float vfloat4 __attribute__((ext_vector_type(4)));

#define THREADS        256
#define POS_PER_TH     8
#define POS_PER_BLOCK  (THREADS * POS_PER_TH)      // 2048 positions / block
#define NBLOCKS        (N_POS / POS_PER_BLOCK)     // 512 blocks = 2 per CU, exact
#define CHUNKS_PER_BLOCK (POS_PER_BLOCK * 16)      // 32768 float4 = 512 KB out
#define EMB_ROWS       (NBINS + 1)                 // 257
#define EMB_CHUNKS     (EMB_ROWS * 16)             // 4112 float4 = 65,792 B

__global__ __launch_bounds__(THREADS, 2)
void BinEmbedding_49520972923592_kernel(
    const float* __restrict__ x,        // (B*L) fp32
    const float* __restrict__ bins,     // (256) fp32, sorted
    const vfloat4* __restrict__ embv,   // (257,64) fp32 = 16 float4 chunks/row
    vfloat4* __restrict__ out)          // (B*L,64) fp32 = 16 float4 chunks/row
{
    __shared__ vfloat4 s_emb[EMB_CHUNKS];        // 65,792 B — whole emb table
    __shared__ float   s_bins[NBINS];            //  1,024 B
    __shared__ int     s_tok[POS_PER_BLOCK];     //  8,192 B  (total 75,008 B)

    const int tid = threadIdx.x;
    const long pbase = (long)blockIdx.x * POS_PER_BLOCK;

    // ---- Staging: bins + full emb table into LDS; x into registers --------
    s_bins[tid] = bins[tid];                     // blockDim == NBINS == 256
#pragma unroll
    for (int c = tid, k = 0; k < EMB_CHUNKS / THREADS + 1; ++k, c += THREADS)
        if (c < EMB_CHUNKS) s_emb[c] = embv[c];  // coalesced dwordx4

    float xv[POS_PER_TH];
#pragma unroll
    for (int j = 0; j < POS_PER_TH; ++j)         // coalesced, 8 loads in flight
        xv[j] = x[pbase + j * THREADS + tid];

    __syncthreads();                              // drain #1 (no stores yet)

    // ---- Phase 1: all 2048 tokens for the block (8 searches / thread) -----
    // count = #bins <= xv (branchless upper-bound search; NaN -> cnt = 0).
    // 8 independent dependent-LDS chains run in parallel (ILP hides latency).
    int cnt[POS_PER_TH];
#pragma unroll
    for (int j = 0; j < POS_PER_TH; ++j) cnt[j] = 0;
#pragma unroll
    for (int step = 128; step >= 1; step >>= 1) {
#pragma unroll
        for (int j = 0; j < POS_PER_TH; ++j) {
            const int cand = cnt[j] + step;
            cnt[j] = (s_bins[cand - 1] <= xv[j]) ? cand : cnt[j];
        }
    }
#pragma unroll
    for (int j = 0; j < POS_PER_TH; ++j) {
        const int c = cnt[j] + ((s_bins[NBINS - 1] <= xv[j]) ? 1 : 0);
        // tok = NaN ? 0 : max(count, 1) (== clamp(searchsorted_right-1,0)+1)
        s_tok[j * THREADS + tid] = (xv[j] != xv[j]) ? 0 : (c > 0 ? c : 1);
    }

    __syncthreads();                              // drain #2 (no stores yet)

    // ---- Phase 2: 128 uninterrupted coalesced float4 stores / thread ------
    // Iteration k: consecutive threads -> consecutive chunks (wave stores
    // 1 KB contiguous). No barriers, no global loads: store queue free-runs
    // to endpgm, like the fill kernel. s_tok read: broadcast per 16 lanes;
    // s_emb read: 4 x 256 B rows / wave = uniform 8 words/bank, conflict-free.
    const long cbase = (long)blockIdx.x * CHUNKS_PER_BLOCK;
    const int  c4    = tid & 15;                  // chunk-in-row, fixed per thread
    const int  g16   = tid >> 4;                  // 16-lane group id
#pragma unroll 8
    for (int k = 0; k < CHUNKS_PER_BLOCK / THREADS; ++k) {   // 128 iterations
        const int tok = s_tok[k * (THREADS / 16) + g16];
        out[cbase + k * THREADS + tid] = s_emb[tok * 16 + c4];
    }
}

extern "C" void kernel_launch(void* const* d_in, const int* in_sizes, int n_in,
                              void* d_out, int out_size, void* d_ws, size_t ws_size,
                              hipStream_t stream) {
    const float*   x    = (const float*)d_in[0];    // (16,65536) fp32
    const float*   bins = (const float*)d_in[1];    // (256,) fp32
    const vfloat4* emb  = (const vfloat4*)d_in[2];  // (257,64) fp32 chunks
    vfloat4* out = (vfloat4*)d_out;                 // (16,65536,64) fp32 chunks

    // 512 blocks x 2048 positions = 1,048,576 = exact cover; 2 blocks/CU.
    const dim3 grid(NBLOCKS), block(THREADS);
    hipLaunchKernelGGL(BinEmbedding_49520972923592_kernel, grid, block, 0, stream,
                       x, bins, emb, out);
}

// Round 3
// 263.644 us; speedup vs baseline: 1.0315x; 1.0027x over previous
//
#include <hip/hip_runtime.h>
#include <stdint.h>

// Problem constants (fixed by the reference file)
#define N_POS (16 * 65536)   // B * L = 1,048,576 positions
#define NBINS 256
#define HDIM  64

// ROUND 13 THEORY (discriminating probe):
//  - Kernel absent from top-5 dispatches (cutoff ~164 us) => kernel < 164 us;
//    dur_us includes harness fills. Two fits: fills=207 + kernel ~54 (at
//    floor) OR fills=166 + kernel ~98 (issue/latency-bound store loop).
//  - Store BW needs only 10.5 B/cyc/CU and LDS gives 85 B/cyc => if the
//    kernel is slow it can only be ISSUE-bound. Probe: cut hot-loop issue
//    slots ~15% by reading tokens as int4 from a transposed token buffer
//    (32 ds_read_b128 replaces 128 ds_read_b32 per thread).
//  - s_tokT[p&15][p>>4], pitch 132: writer = 2 lanes/bank (free, m136);
//    reader = 4 broadcast addrs/wave, 16B-aligned (528 B row pitch).
//  - Pre-commit: neutral result (+-4 us) => declare ROOFLINE next round
//    (floor arithmetic: fills ~207 + 41 write + ~9 prologue/launch ~= 259).

typedef float vfloat4 __attribute__((ext_vector_type(4)));
typedef int   vint4   __attribute__((ext_vector_type(4)));

#define THREADS        256
#define POS_PER_TH     8
#define POS_PER_BLOCK  (THREADS * POS_PER_TH)      // 2048 positions / block
#define NBLOCKS        (N_POS / POS_PER_BLOCK)     // 512 blocks = 2 per CU, exact
#define CHUNKS_PER_BLOCK (POS_PER_BLOCK * 16)      // 32768 float4 = 512 KB out
#define EMB_ROWS       (NBINS + 1)                 // 257
#define EMB_CHUNKS     (EMB_ROWS * 16)             // 4112 float4 = 65,792 B
#define TOKT_PITCH     132                         // ints; 528 B rows (16B-aligned)

__global__ __launch_bounds__(THREADS, 2)
void BinEmbedding_49520972923592_kernel(
    const float* __restrict__ x,        // (B*L) fp32
    const float* __restrict__ bins,     // (256) fp32, sorted
    const vfloat4* __restrict__ embv,   // (257,64) fp32 = 16 float4 chunks/row
    vfloat4* __restrict__ out)          // (B*L,64) fp32 = 16 float4 chunks/row
{
    __shared__ vfloat4 s_emb[EMB_CHUNKS];          // 65,792 B
    __shared__ float   s_bins[NBINS];              //  1,024 B
    __shared__ int     s_tokT[16 * TOKT_PITCH];    //  8,448 B (total 75,264 B)

    const int tid = threadIdx.x;
    const long pbase = (long)blockIdx.x * POS_PER_BLOCK;

    // ---- Staging: bins + full emb table into LDS; x into registers --------
    s_bins[tid] = bins[tid];                       // blockDim == NBINS == 256
#pragma unroll
    for (int c = tid, k = 0; k < EMB_CHUNKS / THREADS + 1; ++k, c += THREADS)
        if (c < EMB_CHUNKS) s_emb[c] = embv[c];    // coalesced dwordx4

    float xv[POS_PER_TH];
#pragma unroll
    for (int j = 0; j < POS_PER_TH; ++j)           // coalesced, 8 loads in flight
        xv[j] = x[pbase + j * THREADS + tid];

    __syncthreads();                               // drain #1 (no stores yet)

    // ---- Phase 1: all 2048 tokens (8 searches / thread, ILP-parallel) -----
    int cnt[POS_PER_TH];
#pragma unroll
    for (int j = 0; j < POS_PER_TH; ++j) cnt[j] = 0;
#pragma unroll
    for (int step = 128; step >= 1; step >>= 1) {
#pragma unroll
        for (int j = 0; j < POS_PER_TH; ++j) {
            const int cand = cnt[j] + step;
            cnt[j] = (s_bins[cand - 1] <= xv[j]) ? cand : cnt[j];
        }
    }
    // Transposed store: position p = j*256+tid -> s_tokT[p&15][p>>4] with
    // p&15 = tid&15, p>>4 = j*16 + (tid>>4). Bank check: 2 lanes/bank (free).
#pragma unroll
    for (int j = 0; j < POS_PER_TH; ++j) {
        const int c = cnt[j] + ((s_bins[NBINS - 1] <= xv[j]) ? 1 : 0);
        // tok = NaN ? 0 : max(count, 1) (== clamp(searchsorted_right-1,0)+1)
        const int tok = (xv[j] != xv[j]) ? 0 : (c > 0 ? c : 1);
        s_tokT[(tid & 15) * TOKT_PITCH + j * 16 + (tid >> 4)] = tok;
    }

    __syncthreads();                               // drain #2 (no stores yet)

    // ---- Phase 2: 128 uninterrupted coalesced float4 stores / thread ------
    // Iteration k: chunk l = k*256+tid, position p = l>>4 = k*16 + (tid>>4).
    // Token read: this thread's sequence lives at s_tokT[(tid>>4)*132 + k],
    // contiguous in k -> int4 reads, 4 broadcast addrs/wave, conflict-free.
    // emb read: 4 x 256 B rows / wave = uniform 8 words/bank, conflict-free.
    // No barriers, no global loads after this point: store queue free-runs.
    const long cbase = (long)blockIdx.x * CHUNKS_PER_BLOCK;
    const int  c4    = tid & 15;                   // chunk-in-row (fixed)
    const vint4* tokp =
        reinterpret_cast<const vint4*>(&s_tokT[(tid >> 4) * TOKT_PITCH]);
#pragma unroll 4
    for (int k4 = 0; k4 < 32; ++k4) {              // 32 x (1 tok read + 4 stores)
        const vint4 t4 = tokp[k4];
#pragma unroll
        for (int m = 0; m < 4; ++m) {
            const int k = k4 * 4 + m;
            out[cbase + k * THREADS + tid] = s_emb[t4[m] * 16 + c4];
        }
    }
}

extern "C" void kernel_launch(void* const* d_in, const int* in_sizes, int n_in,
                              void* d_out, int out_size, void* d_ws, size_t ws_size,
                              hipStream_t stream) {
    const float*   x    = (const float*)d_in[0];    // (16,65536) fp32
    const float*   bins = (const float*)d_in[1];    // (256,) fp32
    const vfloat4* emb  = (const vfloat4*)d_in[2];  // (257,64) fp32 chunks
    vfloat4* out = (vfloat4*)d_out;                 // (16,65536,64) fp32 chunks

    // 512 blocks x 2048 positions = 1,048,576 = exact cover; 2 blocks/CU.
    const dim3 grid(NBLOCKS), block(THREADS);
    hipLaunchKernelGGL(BinEmbedding_49520972923592_kernel, grid, block, 0, stream,
                       x, bins, emb, out);
}